// Round 10
// baseline (1252.981 us; speedup 1.0000x reference)
//
#include <hip/hip_runtime.h>
#include <hip/hip_bf16.h>

// GCN layer: h = x@W; symmetric-norm aggregation with self-loops; +b, relu, log_softmax.
// Decomposition: g[i] = (x[i]@W)*dinv[i]; out[c] = LSM(relu(dinv[c]*(g[c]+sum_{e:col=c} g[row_e]) + b))
// R6 design (unmeasured: R7/R8/R9 GPU timeouts; resubmitted unchanged):
//   fill_csr had 105MB WRITE_SIZE (16x amplification from 1.6M random 4B scatters)
//   -> 128-node bucket binning: 782 sequential write streams (active lines ~50KB, L2-held),
//      then per-bucket LDS-accumulator aggregate (fuses CSR walk + finalize; also
//      eliminates count_deg's 1.6M global atomics via per-bucket LDS histograms).

#define IN_CH 128
#define OUT_CH 64
#define NPAD 100352        // N rounded up; workspace stride
#define BSHIFT 7           // bucket width = 128 nodes
#define BW 128             // nodes per bucket
#define MAXNB 1024         // max buckets (scan kernel width)

// ---------------- bucket histogram: bcount[col>>7]++ (LDS-staged) ----------------
__global__ __launch_bounds__(256) void bucket_count_kernel(
    const int* __restrict__ cols, int* __restrict__ bcount, int E, int NB)
{
    __shared__ int h[MAXNB];
    const int tid = threadIdx.x;
    for (int i = tid; i < NB; i += 256) h[i] = 0;
    __syncthreads();
    for (int i = blockIdx.x * 256 + tid; i < E; i += gridDim.x * 256)
        atomicAdd(&h[cols[i] >> BSHIFT], 1);
    __syncthreads();
    for (int i = tid; i < NB; i += 256)
        if (h[i]) atomicAdd(&bcount[i], h[i]);
}

// ---------------- single-block scan over NB buckets -> boffset, bcursor ----------------
__global__ __launch_bounds__(MAXNB) void bucket_scan_kernel(
    const int* __restrict__ bcount, int* __restrict__ boffset,
    int* __restrict__ bcursor, int NB, int E)
{
    __shared__ int sdata[MAXNB];
    const int tid = threadIdx.x;
    const int v = (tid < NB) ? bcount[tid] : 0;
    sdata[tid] = v;
    __syncthreads();
    for (int off = 1; off < MAXNB; off <<= 1) {
        int t = 0;
        if (tid >= off) t = sdata[tid - off];
        __syncthreads();
        sdata[tid] += t;
        __syncthreads();
    }
    if (tid < NB) {
        const int excl = sdata[tid] - v;
        boffset[tid] = excl;
        bcursor[tid] = excl;
    }
    if (tid == 0) boffset[NB] = E;
}

// ---------------- bin edges: binned[p++] = row | (col&127)<<20 ----------------
// 782 active sequential write streams -> L2-resident lines -> compact writeback.
__global__ __launch_bounds__(256) void bin_edges_kernel(
    const int* __restrict__ rows, const int* __restrict__ cols,
    int* __restrict__ bcursor, int* __restrict__ binned, int E)
{
    for (int i = blockIdx.x * 256 + threadIdx.x; i < E; i += gridDim.x * 256) {
        const int c = cols[i];
        const int bkt = c >> BSHIFT;
        const int p = atomicAdd(&bcursor[bkt], 1);
        binned[p] = rows[i] | ((c & (BW - 1)) << 20);
    }
}

// ---------------- per-bucket degree hist -> dinv = rsqrt(deg+1) ----------------
__global__ __launch_bounds__(256) void deg_dinv_kernel(
    const int* __restrict__ binned, const int* __restrict__ boffset,
    float* __restrict__ dinv, int N, int NB)
{
    __shared__ int h[BW];
    const int tid = threadIdx.x;
    const int b = blockIdx.x;
    const int lo = b << BSHIFT;
    const int w = min(BW, N - lo);
    if (tid < BW) h[tid] = 0;
    __syncthreads();
    const int s0 = boffset[b], s1 = boffset[b + 1];
    for (int e = s0 + tid; e < s1; e += 256)
        atomicAdd(&h[binned[e] >> 20], 1);
    __syncthreads();
    if (tid < w) dinv[lo + tid] = rsqrtf((float)h[tid] + 1.0f);
}

// ---------------- g = (x @ W) * dinv ----------------
// Barrier-free: each wave independently owns rows (4 waves/block, wave-private LDS slice).
__global__ __launch_bounds__(256) void gemm_scale_kernel(
    const float* __restrict__ x, const float* __restrict__ W,
    const float* __restrict__ dinv, float* __restrict__ g, int N)
{
    __shared__ float xs[4][IN_CH];           // 2 KB, one 512B slice per wave

    const int wave = threadIdx.x >> 6;
    const int lane = threadIdx.x & 63;

    float Wreg[IN_CH];                       // lane's W column, statically indexed
    #pragma unroll
    for (int k = 0; k < IN_CH; ++k) Wreg[k] = W[k * OUT_CH + lane];

    const int wid    = blockIdx.x * 4 + wave;
    const int stride = gridDim.x * 4;

    for (int r = wid; r < N; r += stride) {
        float2 v = *reinterpret_cast<const float2*>(x + (size_t)r * IN_CH + lane * 2);
        xs[wave][lane * 2]     = v.x;
        xs[wave][lane * 2 + 1] = v.y;
        const float4* xv = reinterpret_cast<const float4*>(xs[wave]);
        float sum = 0.f;
        #pragma unroll
        for (int k4 = 0; k4 < IN_CH / 4; ++k4) {
            float4 xk = xv[k4];              // broadcast read (all lanes same addr)
            sum = fmaf(xk.x, Wreg[4 * k4 + 0], sum);
            sum = fmaf(xk.y, Wreg[4 * k4 + 1], sum);
            sum = fmaf(xk.z, Wreg[4 * k4 + 2], sum);
            sum = fmaf(xk.w, Wreg[4 * k4 + 3], sum);
        }
        g[(size_t)r * OUT_CH + lane] = sum * dinv[r];
    }
}

// ---------------- aggregate + finalize: one block per bucket ----------------
// LDS acc[128][64]: init = g[own] (self-loop); stream bucket edges, gather g[row],
// LDS-atomicAdd into acc[local] (lane-consecutive words = 2-way bank alias = free);
// finalize (dinv scale, bias, relu, LSM) -> out.
__global__ __launch_bounds__(512) void aggregate_kernel(
    const float* __restrict__ g, const int* __restrict__ binned,
    const int* __restrict__ boffset, const float* __restrict__ dinv,
    const float* __restrict__ bias, float* __restrict__ out, int N, int NB)
{
    __shared__ float acc[BW * OUT_CH];       // 32 KB -> 4 blocks/CU
    const int wave = threadIdx.x >> 6;       // 8 waves
    const int lane = threadIdx.x & 63;
    const int b = blockIdx.x;
    const int lo = b << BSHIFT;
    const int w = min(BW, N - lo);

    // init: self-loop term
    for (int j = wave; j < w; j += 8)
        acc[j * OUT_CH + lane] = g[(size_t)(lo + j) * OUT_CH + lane];
    __syncthreads();

    const int s0 = boffset[b], s1 = boffset[b + 1];
    // each wave processes 64-edge chunks, stride 8 waves
    for (int chunk = s0 + wave * 64; chunk < s1; chunk += 8 * 64) {
        const int cnt = min(64, s1 - chunk);
        int pk = 0;
        if (lane < cnt) pk = binned[chunk + lane];   // coalesced
        int k = 0;
        for (; k + 4 <= cnt; k += 4) {               // 4 gathers in flight
            const int p0 = __shfl(pk, k + 0), p1 = __shfl(pk, k + 1);
            const int p2 = __shfl(pk, k + 2), p3 = __shfl(pk, k + 3);
            const float v0 = g[(size_t)(p0 & 0xFFFFF) * OUT_CH + lane];
            const float v1 = g[(size_t)(p1 & 0xFFFFF) * OUT_CH + lane];
            const float v2 = g[(size_t)(p2 & 0xFFFFF) * OUT_CH + lane];
            const float v3 = g[(size_t)(p3 & 0xFFFFF) * OUT_CH + lane];
            atomicAdd(&acc[(p0 >> 20) * OUT_CH + lane], v0);
            atomicAdd(&acc[(p1 >> 20) * OUT_CH + lane], v1);
            atomicAdd(&acc[(p2 >> 20) * OUT_CH + lane], v2);
            atomicAdd(&acc[(p3 >> 20) * OUT_CH + lane], v3);
        }
        for (; k < cnt; ++k) {
            const int p = __shfl(pk, k);
            const float v = g[(size_t)(p & 0xFFFFF) * OUT_CH + lane];
            atomicAdd(&acc[(p >> 20) * OUT_CH + lane], v);
        }
    }
    __syncthreads();

    // finalize own nodes
    for (int j = wave; j < w; j += 8) {
        const int c = lo + j;
        float v = acc[j * OUT_CH + lane] * dinv[c] + bias[lane];
        v = fmaxf(v, 0.0f);
        float m = v;
        #pragma unroll
        for (int off = 32; off > 0; off >>= 1) m = fmaxf(m, __shfl_xor(m, off));
        float ex = expf(v - m);
        float s = ex;
        #pragma unroll
        for (int off = 32; off > 0; off >>= 1) s += __shfl_xor(s, off);
        out[(size_t)c * OUT_CH + lane] = v - m - logf(s);
    }
}

// ============ fallback path (small ws / out-of-range N): float-atomic scatter ============
__global__ void fb_count_kernel(const int* __restrict__ cols, float* __restrict__ deg, int E) {
    int i = blockIdx.x * blockDim.x + threadIdx.x;
    if (i < E) atomicAdd(&deg[cols[i]], 1.0f);
}
__global__ void fb_dinv_kernel(float* __restrict__ deg, int N) {
    int i = blockIdx.x * blockDim.x + threadIdx.x;
    if (i < N) deg[i] = rsqrtf(deg[i] + 1.0f);
}
__global__ __launch_bounds__(256) void fb_gemm_kernel(
    const float* __restrict__ x, const float* __restrict__ W,
    const float* __restrict__ dinv, float* __restrict__ g, float* __restrict__ acc, int N)
{
    __shared__ float xs[4][IN_CH];
    const int wave = threadIdx.x >> 6;
    const int lane = threadIdx.x & 63;
    float Wreg[IN_CH];
    #pragma unroll
    for (int k = 0; k < IN_CH; ++k) Wreg[k] = W[k * OUT_CH + lane];
    const int wid    = blockIdx.x * 4 + wave;
    const int stride = gridDim.x * 4;
    for (int r = wid; r < N; r += stride) {
        float2 v = *reinterpret_cast<const float2*>(x + (size_t)r * IN_CH + lane * 2);
        xs[wave][lane * 2] = v.x; xs[wave][lane * 2 + 1] = v.y;
        const float4* xv = reinterpret_cast<const float4*>(xs[wave]);
        float sum = 0.f;
        #pragma unroll
        for (int k4 = 0; k4 < IN_CH / 4; ++k4) {
            float4 xk = xv[k4];
            sum = fmaf(xk.x, Wreg[4 * k4 + 0], sum);
            sum = fmaf(xk.y, Wreg[4 * k4 + 1], sum);
            sum = fmaf(xk.z, Wreg[4 * k4 + 2], sum);
            sum = fmaf(xk.w, Wreg[4 * k4 + 3], sum);
        }
        const float gv = sum * dinv[r];
        g[(size_t)r * OUT_CH + lane] = gv;
        acc[(size_t)r * OUT_CH + lane] = gv;
    }
}
__global__ __launch_bounds__(256) void fb_scatter_kernel(
    const int* __restrict__ rows, const int* __restrict__ cols,
    const float* __restrict__ g, float* __restrict__ acc, int E)
{
    const int e = blockIdx.x * 4 + (threadIdx.x >> 6);
    if (e >= E) return;
    const int lane = threadIdx.x & 63;
    atomicAdd(&acc[(size_t)cols[e] * OUT_CH + lane], g[(size_t)rows[e] * OUT_CH + lane]);
}
__global__ __launch_bounds__(256) void fb_finalize_kernel(
    float* __restrict__ acc, const float* __restrict__ dinv, const float* __restrict__ b, int N)
{
    const int r = blockIdx.x * 4 + (threadIdx.x >> 6);
    if (r >= N) return;
    const int lane = threadIdx.x & 63;
    float v = acc[(size_t)r * OUT_CH + lane] * dinv[r] + b[lane];
    v = fmaxf(v, 0.0f);
    float m = v;
    #pragma unroll
    for (int off = 32; off > 0; off >>= 1) m = fmaxf(m, __shfl_xor(m, off));
    float ex = expf(v - m);
    float s = ex;
    #pragma unroll
    for (int off = 32; off > 0; off >>= 1) s += __shfl_xor(s, off);
    acc[(size_t)r * OUT_CH + lane] = v - m - logf(s);
}

extern "C" void kernel_launch(void* const* d_in, const int* in_sizes, int n_in,
                              void* d_out, int out_size, void* d_ws, size_t ws_size,
                              hipStream_t stream) {
    const float* x  = (const float*)d_in[0];
    const int*   ei = (const int*)d_in[1];
    const float* W  = (const float*)d_in[2];
    const float* b  = (const float*)d_in[3];
    float* out = (float*)d_out;

    const int N = in_sizes[0] / IN_CH;       // 100000
    const int E = in_sizes[1] / 2;           // 1600000
    const int* rows = ei;                    // edge_index[0] = src
    const int* cols = ei + E;                // edge_index[1] = dst
    const int NB = (N + BW - 1) >> BSHIFT;   // 782 buckets

    // workspace layout (4-byte units):
    //   dinv[NPAD] | bcount[2048] | boffset[2048] | bcursor[2048] | binned[Epad] | g[N*64]
    const size_t Epad = ((size_t)E + 127) & ~(size_t)127;
    const size_t need = ((size_t)NPAD + 6144 + Epad + (size_t)N * OUT_CH) * 4;

    if (ws_size >= need && NB <= MAXNB && N < (1 << 20)) {
        float* dinv    = (float*)d_ws;
        int*   bcount  = (int*)d_ws + NPAD;
        int*   boffset = (int*)d_ws + NPAD + 2048;
        int*   bcursor = (int*)d_ws + NPAD + 4096;
        int*   binned  = (int*)d_ws + NPAD + 6144;
        float* g       = (float*)d_ws + NPAD + 6144 + Epad;

        hipMemsetAsync(bcount, 0, (size_t)NB * sizeof(int), stream);
        bucket_count_kernel<<<256, 256, 0, stream>>>(cols, bcount, E, NB);
        bucket_scan_kernel<<<1, MAXNB, 0, stream>>>(bcount, boffset, bcursor, NB, E);
        bin_edges_kernel<<<2048, 256, 0, stream>>>(rows, cols, bcursor, binned, E);
        deg_dinv_kernel<<<NB, 256, 0, stream>>>(binned, boffset, dinv, N, NB);
        gemm_scale_kernel<<<2048, 256, 0, stream>>>(x, W, dinv, g, N);
        aggregate_kernel<<<NB, 512, 0, stream>>>(g, binned, boffset, dinv, b, out, N, NB);
    } else {
        // fallback: atomic scatter (needs dinv[NPAD] + g[N*64] floats)
        float* deg = (float*)d_ws;
        float* g   = (float*)d_ws + NPAD;
        hipMemsetAsync(deg, 0, (size_t)N * sizeof(float), stream);
        fb_count_kernel<<<(E + 255) / 256, 256, 0, stream>>>(cols, deg, E);
        fb_dinv_kernel<<<(N + 255) / 256, 256, 0, stream>>>(deg, N);
        fb_gemm_kernel<<<2048, 256, 0, stream>>>(x, W, deg, g, out, N);
        fb_scatter_kernel<<<(E + 3) / 4, 256, 0, stream>>>(rows, cols, g, out, E);
        fb_finalize_kernel<<<(N + 3) / 4, 256, 0, stream>>>(out, deg, b, N);
    }
}

// Round 11
// 249.833 us; speedup vs baseline: 5.0153x; 5.0153x over previous
//
#include <hip/hip_runtime.h>
#include <hip/hip_bf16.h>

// GCN layer: h = x@W; symmetric-norm aggregation with self-loops; +b, relu, log_softmax.
// Decomposition: g[i] = (x[i]@W)*dinv[i]; out[c] = LSM(relu(dinv[c]*(g[c]+sum_{e:col=c} g[row_e]) + b))
// R10 post-mortem: R6 bucket-LDS aggregate was latency-bound (728us, VALUBusy 3.9%, 296GB/s:
//   782 blocks x 4-deep = too few outstanding gathers). Revert aggregate to R5 wave-per-node
//   register ladder (measured <=127us) fed by a node-sorted CSR built WITHOUT write
//   amplification: tile-staged bucket binning (reservation atomics, compact streams) +
//   per-bucket LDS counting sort. binned overlays g (used before gemm) to keep ws ~33MB.

#define IN_CH 128
#define OUT_CH 64
#define NPAD 100352        // N rounded up; workspace stride (>= N+1)
#define BSHIFT 7           // bucket width = 128 nodes
#define BW 128             // nodes per bucket
#define MAXNB 1024         // max buckets
#define TILE 4096          // edges staged per block in bin_edges

// ---------------- bucket histogram: bcount[col>>7]++ (LDS-staged) ----------------
__global__ __launch_bounds__(256) void bucket_count_kernel(
    const int* __restrict__ cols, int* __restrict__ bcount, int E, int NB)
{
    __shared__ int h[MAXNB];
    const int tid = threadIdx.x;
    for (int i = tid; i < NB; i += 256) h[i] = 0;
    __syncthreads();
    for (int i = blockIdx.x * 256 + tid; i < E; i += gridDim.x * 256)
        atomicAdd(&h[cols[i] >> BSHIFT], 1);
    __syncthreads();
    for (int i = tid; i < NB; i += 256)
        if (h[i]) atomicAdd(&bcount[i], h[i]);
}

// ---------------- single-block scan over NB buckets -> boffset, bcursor ----------------
__global__ __launch_bounds__(MAXNB) void bucket_scan_kernel(
    const int* __restrict__ bcount, int* __restrict__ boffset,
    int* __restrict__ bcursor, int NB, int E)
{
    __shared__ int sdata[MAXNB];
    const int tid = threadIdx.x;
    const int v = (tid < NB) ? bcount[tid] : 0;
    sdata[tid] = v;
    __syncthreads();
    for (int off = 1; off < MAXNB; off <<= 1) {
        int t = 0;
        if (tid >= off) t = sdata[tid - off];
        __syncthreads();
        sdata[tid] += t;
        __syncthreads();
    }
    if (tid < NB) {
        const int excl = sdata[tid] - v;
        boffset[tid] = excl;
        bcursor[tid] = excl;
    }
    if (tid == 0) boffset[NB] = E;
}

// ---------------- bin edges (tile-staged, reservation atomics) ----------------
// Stage TILE edges in LDS; per-block LDS hist; ONE global reservation atomic per
// (block,bucket) (306k total vs 1.6M, 5x less same-address serialization); per-edge
// positions from LDS cursors. binned[p] = row | (col&127)<<20.
__global__ __launch_bounds__(256) void bin_edges_kernel(
    const int* __restrict__ rows, const int* __restrict__ cols,
    int* __restrict__ bcursor, int* __restrict__ binned, int E, int NB)
{
    __shared__ int v[TILE];                  // 16 KB packed edge words
    __shared__ unsigned short bk[TILE];      // 8 KB bucket ids
    __shared__ int hist[MAXNB];              // 4 KB
    __shared__ int cur[MAXNB];               // 4 KB
    const int tid = threadIdx.x;
    const int base = blockIdx.x * TILE;
    const int n = min(TILE, E - base);

    for (int i = tid; i < NB; i += 256) hist[i] = 0;
    __syncthreads();
    for (int j = tid; j < n; j += 256) {
        const int c = cols[base + j];
        const int b = c >> BSHIFT;
        v[j] = rows[base + j] | ((c & (BW - 1)) << 20);
        bk[j] = (unsigned short)b;
        atomicAdd(&hist[b], 1);
    }
    __syncthreads();
    for (int i = tid; i < NB; i += 256)
        cur[i] = hist[i] ? atomicAdd(&bcursor[i], hist[i]) : 0;
    __syncthreads();
    for (int j = tid; j < n; j += 256) {
        const int p = atomicAdd(&cur[bk[j]], 1);
        binned[p] = v[j];
    }
}

// ---------------- per-bucket counting sort -> node-sorted csr_src, rowstart, dinv ----------------
// Reads the bucket's binned segment; LDS hist[128]+scan gives per-node offsets; scatter
// writes stay inside the bucket's own ~8KB window (compact writeback).
__global__ __launch_bounds__(256) void sort_bucket_kernel(
    const int* __restrict__ binned, const int* __restrict__ boffset,
    int* __restrict__ csr_src, int* __restrict__ rowstart,
    float* __restrict__ dinv, int N, int E, int NB)
{
    __shared__ int hist[BW];
    __shared__ int sc[BW];
    __shared__ int cur[BW];
    const int tid = threadIdx.x;
    const int b = blockIdx.x;
    const int lo = b << BSHIFT;
    const int w = min(BW, N - lo);
    const int s0 = boffset[b], s1 = boffset[b + 1];

    if (tid < BW) hist[tid] = 0;
    __syncthreads();
    for (int e = s0 + tid; e < s1; e += 256)
        atomicAdd(&hist[binned[e] >> 20], 1);
    __syncthreads();
    if (tid < BW) sc[tid] = hist[tid];
    __syncthreads();
    for (int off = 1; off < BW; off <<= 1) {       // Hillis-Steele inclusive scan
        int t = 0;
        if (tid >= off && tid < BW) t = sc[tid - off];
        __syncthreads();
        if (tid >= off && tid < BW) sc[tid] += t;
        __syncthreads();
    }
    if (tid < BW) {
        const int abs0 = s0 + sc[tid] - hist[tid]; // absolute exclusive base
        cur[tid] = abs0;
        if (tid < w) {
            rowstart[lo + tid] = abs0;
            dinv[lo + tid] = rsqrtf((float)hist[tid] + 1.0f);
        }
    }
    if (b == NB - 1 && tid == 0) rowstart[N] = E;
    __syncthreads();
    for (int e = s0 + tid; e < s1; e += 256) {
        const int pv = binned[e];
        const int p = atomicAdd(&cur[pv >> 20], 1);
        csr_src[p] = pv & 0xFFFFF;
    }
}

// ---------------- g = (x @ W) * dinv ----------------
// Barrier-free: each wave independently owns rows (4 waves/block, wave-private LDS slice).
__global__ __launch_bounds__(256) void gemm_scale_kernel(
    const float* __restrict__ x, const float* __restrict__ W,
    const float* __restrict__ dinv, float* __restrict__ g, int N)
{
    __shared__ float xs[4][IN_CH];           // 2 KB, one 512B slice per wave

    const int wave = threadIdx.x >> 6;
    const int lane = threadIdx.x & 63;

    float Wreg[IN_CH];                       // lane's W column, statically indexed
    #pragma unroll
    for (int k = 0; k < IN_CH; ++k) Wreg[k] = W[k * OUT_CH + lane];

    const int wid    = blockIdx.x * 4 + wave;
    const int stride = gridDim.x * 4;

    for (int r = wid; r < N; r += stride) {
        float2 v = *reinterpret_cast<const float2*>(x + (size_t)r * IN_CH + lane * 2);
        xs[wave][lane * 2]     = v.x;
        xs[wave][lane * 2 + 1] = v.y;
        const float4* xv = reinterpret_cast<const float4*>(xs[wave]);
        float sum = 0.f;
        #pragma unroll
        for (int k4 = 0; k4 < IN_CH / 4; ++k4) {
            float4 xk = xv[k4];              // broadcast read (all lanes same addr)
            sum = fmaf(xk.x, Wreg[4 * k4 + 0], sum);
            sum = fmaf(xk.y, Wreg[4 * k4 + 1], sum);
            sum = fmaf(xk.z, Wreg[4 * k4 + 2], sum);
            sum = fmaf(xk.w, Wreg[4 * k4 + 3], sum);
        }
        g[(size_t)r * OUT_CH + lane] = sum * dinv[r];
    }
}

// ---------------- aggregate + finalize (wave per node, register acc) ----------------
// R5-proven structure: 100k waves, 8/4/2/1 gather ladder -> high memory-level parallelism.
__global__ __launch_bounds__(256) void aggregate_kernel(
    const float* __restrict__ g, const int* __restrict__ rowstart,
    const int* __restrict__ csr_src, const float* __restrict__ dinv,
    const float* __restrict__ b, float* __restrict__ out, int N)
{
    const int r = blockIdx.x * 4 + (threadIdx.x >> 6);   // wave-uniform
    if (r >= N) return;
    const int lane = threadIdx.x & 63;

    const int s0 = rowstart[r];
    const int s1 = rowstart[r + 1];

    float acc = g[(size_t)r * OUT_CH + lane];   // self-loop term
    for (int base = s0; base < s1; base += 64) {
        const int cnt = min(64, s1 - base);
        int src = 0;
        if (lane < cnt) src = csr_src[base + lane];
        int k = 0;
        if (cnt >= 8) {
            float a0 = 0.f, a1 = 0.f, a2 = 0.f, a3 = 0.f;
            float a4 = 0.f, a5 = 0.f, a6 = 0.f, a7 = 0.f;
            for (; k + 8 <= cnt; k += 8) {
                const int i0 = __shfl(src, k + 0), i1 = __shfl(src, k + 1);
                const int i2 = __shfl(src, k + 2), i3 = __shfl(src, k + 3);
                const int i4 = __shfl(src, k + 4), i5 = __shfl(src, k + 5);
                const int i6 = __shfl(src, k + 6), i7 = __shfl(src, k + 7);
                a0 += g[(size_t)i0 * OUT_CH + lane];
                a1 += g[(size_t)i1 * OUT_CH + lane];
                a2 += g[(size_t)i2 * OUT_CH + lane];
                a3 += g[(size_t)i3 * OUT_CH + lane];
                a4 += g[(size_t)i4 * OUT_CH + lane];
                a5 += g[(size_t)i5 * OUT_CH + lane];
                a6 += g[(size_t)i6 * OUT_CH + lane];
                a7 += g[(size_t)i7 * OUT_CH + lane];
            }
            acc += ((a0 + a1) + (a2 + a3)) + ((a4 + a5) + (a6 + a7));
        }
        if (k + 4 <= cnt) {
            const int i0 = __shfl(src, k + 0), i1 = __shfl(src, k + 1);
            const int i2 = __shfl(src, k + 2), i3 = __shfl(src, k + 3);
            float a0 = g[(size_t)i0 * OUT_CH + lane];
            float a1 = g[(size_t)i1 * OUT_CH + lane];
            float a2 = g[(size_t)i2 * OUT_CH + lane];
            float a3 = g[(size_t)i3 * OUT_CH + lane];
            acc += (a0 + a1) + (a2 + a3);
            k += 4;
        }
        if (k + 2 <= cnt) {
            const int i0 = __shfl(src, k + 0), i1 = __shfl(src, k + 1);
            float a0 = g[(size_t)i0 * OUT_CH + lane];
            float a1 = g[(size_t)i1 * OUT_CH + lane];
            acc += a0 + a1;
            k += 2;
        }
        if (k < cnt)
            acc += g[(size_t)__shfl(src, k) * OUT_CH + lane];
    }

    float v = acc * dinv[r] + b[lane];
    v = fmaxf(v, 0.0f);

    float m = v;
    #pragma unroll
    for (int off = 32; off > 0; off >>= 1) m = fmaxf(m, __shfl_xor(m, off));
    float ex = expf(v - m);
    float s = ex;
    #pragma unroll
    for (int off = 32; off > 0; off >>= 1) s += __shfl_xor(s, off);

    out[(size_t)r * OUT_CH + lane] = v - m - logf(s);
}

// ============ fallback path (small ws / out-of-range N): float-atomic scatter ============
__global__ void fb_count_kernel(const int* __restrict__ cols, float* __restrict__ deg, int E) {
    int i = blockIdx.x * blockDim.x + threadIdx.x;
    if (i < E) atomicAdd(&deg[cols[i]], 1.0f);
}
__global__ void fb_dinv_kernel(float* __restrict__ deg, int N) {
    int i = blockIdx.x * blockDim.x + threadIdx.x;
    if (i < N) deg[i] = rsqrtf(deg[i] + 1.0f);
}
__global__ __launch_bounds__(256) void fb_gemm_kernel(
    const float* __restrict__ x, const float* __restrict__ W,
    const float* __restrict__ dinv, float* __restrict__ g, float* __restrict__ acc, int N)
{
    __shared__ float xs[4][IN_CH];
    const int wave = threadIdx.x >> 6;
    const int lane = threadIdx.x & 63;
    float Wreg[IN_CH];
    #pragma unroll
    for (int k = 0; k < IN_CH; ++k) Wreg[k] = W[k * OUT_CH + lane];
    const int wid    = blockIdx.x * 4 + wave;
    const int stride = gridDim.x * 4;
    for (int r = wid; r < N; r += stride) {
        float2 v = *reinterpret_cast<const float2*>(x + (size_t)r * IN_CH + lane * 2);
        xs[wave][lane * 2] = v.x; xs[wave][lane * 2 + 1] = v.y;
        const float4* xv = reinterpret_cast<const float4*>(xs[wave]);
        float sum = 0.f;
        #pragma unroll
        for (int k4 = 0; k4 < IN_CH / 4; ++k4) {
            float4 xk = xv[k4];
            sum = fmaf(xk.x, Wreg[4 * k4 + 0], sum);
            sum = fmaf(xk.y, Wreg[4 * k4 + 1], sum);
            sum = fmaf(xk.z, Wreg[4 * k4 + 2], sum);
            sum = fmaf(xk.w, Wreg[4 * k4 + 3], sum);
        }
        const float gv = sum * dinv[r];
        g[(size_t)r * OUT_CH + lane] = gv;
        acc[(size_t)r * OUT_CH + lane] = gv;
    }
}
__global__ __launch_bounds__(256) void fb_scatter_kernel(
    const int* __restrict__ rows, const int* __restrict__ cols,
    const float* __restrict__ g, float* __restrict__ acc, int E)
{
    const int e = blockIdx.x * 4 + (threadIdx.x >> 6);
    if (e >= E) return;
    const int lane = threadIdx.x & 63;
    atomicAdd(&acc[(size_t)cols[e] * OUT_CH + lane], g[(size_t)rows[e] * OUT_CH + lane]);
}
__global__ __launch_bounds__(256) void fb_finalize_kernel(
    float* __restrict__ acc, const float* __restrict__ dinv, const float* __restrict__ b, int N)
{
    const int r = blockIdx.x * 4 + (threadIdx.x >> 6);
    if (r >= N) return;
    const int lane = threadIdx.x & 63;
    float v = acc[(size_t)r * OUT_CH + lane] * dinv[r] + b[lane];
    v = fmaxf(v, 0.0f);
    float m = v;
    #pragma unroll
    for (int off = 32; off > 0; off >>= 1) m = fmaxf(m, __shfl_xor(m, off));
    float ex = expf(v - m);
    float s = ex;
    #pragma unroll
    for (int off = 32; off > 0; off >>= 1) s += __shfl_xor(s, off);
    acc[(size_t)r * OUT_CH + lane] = v - m - logf(s);
}

extern "C" void kernel_launch(void* const* d_in, const int* in_sizes, int n_in,
                              void* d_out, int out_size, void* d_ws, size_t ws_size,
                              hipStream_t stream) {
    const float* x  = (const float*)d_in[0];
    const int*   ei = (const int*)d_in[1];
    const float* W  = (const float*)d_in[2];
    const float* b  = (const float*)d_in[3];
    float* out = (float*)d_out;

    const int N = in_sizes[0] / IN_CH;       // 100000
    const int E = in_sizes[1] / 2;           // 1600000
    const int* rows = ei;                    // edge_index[0] = src
    const int* cols = ei + E;                // edge_index[1] = dst
    const int NB = (N + BW - 1) >> BSHIFT;   // 782 buckets
    const int NT = (E + TILE - 1) / TILE;    // 391 bin tiles

    // workspace layout (4-byte units):
    //   dinv[NPAD] | bcount[2048] | boffset[2048] | bcursor[2048] | rowstart[NPAD] |
    //   csr_src[Epad] | g[N*64]   (binned overlays g: used only before gemm runs)
    const size_t Epad = ((size_t)E + 127) & ~(size_t)127;
    const size_t need = ((size_t)NPAD * 2 + 6144 + Epad + (size_t)N * OUT_CH) * 4;

    if (ws_size >= need && NB <= MAXNB && N < (1 << 20)) {
        float* dinv     = (float*)d_ws;
        int*   bcount   = (int*)d_ws + NPAD;
        int*   boffset  = (int*)d_ws + NPAD + 2048;
        int*   bcursor  = (int*)d_ws + NPAD + 4096;
        int*   rowstart = (int*)d_ws + NPAD + 6144;
        int*   csr_src  = (int*)d_ws + 2 * NPAD + 6144;
        float* g        = (float*)d_ws + 2 * NPAD + 6144 + Epad;
        int*   binned   = (int*)g;           // overlay: dead once gemm writes g

        hipMemsetAsync(bcount, 0, (size_t)NB * sizeof(int), stream);
        bucket_count_kernel<<<256, 256, 0, stream>>>(cols, bcount, E, NB);
        bucket_scan_kernel<<<1, MAXNB, 0, stream>>>(bcount, boffset, bcursor, NB, E);
        bin_edges_kernel<<<NT, 256, 0, stream>>>(rows, cols, bcursor, binned, E, NB);
        sort_bucket_kernel<<<NB, 256, 0, stream>>>(binned, boffset, csr_src, rowstart, dinv, N, E, NB);
        gemm_scale_kernel<<<2048, 256, 0, stream>>>(x, W, dinv, g, N);
        aggregate_kernel<<<(N + 3) / 4, 256, 0, stream>>>(g, rowstart, csr_src, dinv, b, out, N);
    } else {
        // fallback: atomic scatter (needs dinv[NPAD] + g[N*64] floats)
        float* deg = (float*)d_ws;
        float* g   = (float*)d_ws + NPAD;
        hipMemsetAsync(deg, 0, (size_t)N * sizeof(float), stream);
        fb_count_kernel<<<(E + 255) / 256, 256, 0, stream>>>(cols, deg, E);
        fb_dinv_kernel<<<(N + 255) / 256, 256, 0, stream>>>(deg, N);
        fb_gemm_kernel<<<2048, 256, 0, stream>>>(x, W, deg, g, out, N);
        fb_scatter_kernel<<<(E + 3) / 4, 256, 0, stream>>>(rows, cols, g, out, E);
        fb_finalize_kernel<<<(N + 3) / 4, 256, 0, stream>>>(out, deg, b, N);
    }
}